// Round 1
// baseline (802.330 us; speedup 1.0000x reference)
//
#include <hip/hip_runtime.h>
#include <hip/hip_bf16.h>
#include <math.h>

#define BATCH 2
#define SEQ 196
#define DMODEL 768
#define NHEAD 12
#define DHEAD 64
#define DFF 3072
#define NROWS (BATCH*SEQ)        // 392
#define NHROWS (NROWS*NHEAD)     // 4704

// ---------- utilities ----------
__device__ __forceinline__ void block_reduce_sum4(float& a, float& b, float& c, float& d,
                                                  float* sbuf /*>=16 floats*/) {
  #pragma unroll
  for (int off = 32; off; off >>= 1) {
    a += __shfl_xor(a, off);
    b += __shfl_xor(b, off);
    c += __shfl_xor(c, off);
    d += __shfl_xor(d, off);
  }
  int wid = threadIdx.x >> 6;
  if ((threadIdx.x & 63) == 0) {
    sbuf[wid*4+0] = a; sbuf[wid*4+1] = b; sbuf[wid*4+2] = c; sbuf[wid*4+3] = d;
  }
  __syncthreads();
  a = sbuf[0] + sbuf[4] + sbuf[8]  + sbuf[12];
  b = sbuf[1] + sbuf[5] + sbuf[9]  + sbuf[13];
  c = sbuf[2] + sbuf[6] + sbuf[10] + sbuf[14];
  d = sbuf[3] + sbuf[7] + sbuf[11] + sbuf[15];
  __syncthreads();
}

// ---------- GEMM: Y[n][m] = X[n][K] @ W[m][K]^T ----------
__global__ __launch_bounds__(256) void gemm_xwt(const float* __restrict__ X,
                                                const float* __restrict__ W,
                                                float* __restrict__ Y,
                                                int n, int K, int m) {
  __shared__ float Xs[16][65];
  __shared__ float Ws[16][65];
  const int tid = threadIdx.x;
  const int tx = tid & 15, ty = tid >> 4;
  const int brow = blockIdx.y * 64, bcol = blockIdx.x * 64;
  float acc[4][4] = {};
  for (int k0 = 0; k0 < K; k0 += 16) {
    #pragma unroll
    for (int l = 0; l < 4; ++l) {
      int i = tid + l*256;        // 0..1023
      int r = i >> 4, kk = i & 15;
      int gr = brow + r;
      Xs[kk][r] = (gr < n) ? X[(size_t)gr*K + k0 + kk] : 0.f;
      Ws[kk][r] = W[(size_t)(bcol + r)*K + k0 + kk];   // m is multiple of 64
    }
    __syncthreads();
    #pragma unroll
    for (int kk = 0; kk < 16; ++kk) {
      float xv[4], wv[4];
      #pragma unroll
      for (int i2 = 0; i2 < 4; ++i2) xv[i2] = Xs[kk][ty*4+i2];
      #pragma unroll
      for (int j2 = 0; j2 < 4; ++j2) wv[j2] = Ws[kk][tx*4+j2];
      #pragma unroll
      for (int i2 = 0; i2 < 4; ++i2)
        #pragma unroll
        for (int j2 = 0; j2 < 4; ++j2) acc[i2][j2] += xv[i2]*wv[j2];
    }
    __syncthreads();
  }
  #pragma unroll
  for (int i2 = 0; i2 < 4; ++i2) {
    int gr = brow + ty*4 + i2;
    if (gr < n) {
      #pragma unroll
      for (int j2 = 0; j2 < 4; ++j2)
        Y[(size_t)gr*m + bcol + tx*4 + j2] = acc[i2][j2];
    }
  }
}

// ---------- hyp_linear post: out = mobius_add(mobius_matvec_scale(MX), bias) ----------
// X: input rows (len din) for xn; MX = X@W^T rows (len dout)
__global__ __launch_bounds__(256) void hyp_linear_post(const float* __restrict__ X,
                                                       const float* __restrict__ MX,
                                                       const float* __restrict__ bias,
                                                       float* __restrict__ out,
                                                       int din, int dout) {
  __shared__ float sbuf[16];
  int r = blockIdx.x;
  const float* xr = X + (size_t)r*din;
  const float* mr = MX + (size_t)r*dout;
  float* orow = out + (size_t)r*dout;
  float xs = 0.f, ms = 0.f, mb = 0.f, bb = 0.f;
  for (int i = threadIdx.x; i < din; i += 256) { float v = xr[i]; xs += v*v; }
  for (int i = threadIdx.x; i < dout; i += 256) {
    float v = mr[i], b = bias[i];
    ms += v*v; mb += v*b; bb += b*b;
  }
  block_reduce_sum4(xs, ms, mb, bb, sbuf);
  float xn  = sqrtf(fmaxf(xs, 1e-15f));
  float mxn = sqrtf(fmaxf(ms, 1e-15f));
  float art = atanhf(fminf(xn, 1.f - 1e-5f));
  float scm = tanhf(mxn/xn*art)/mxn;     // mobius_matvec scale on MX
  // mobius_add(m, bias), m = scm*MX
  float x2 = scm*scm*ms;
  float y2 = bb;
  float xy = scm*mb;
  float den = fmaxf(1.f + 2.f*xy + x2*y2, 1e-15f);
  float ca = (1.f + 2.f*xy + y2) * scm / den;
  float cb = (1.f - x2) / den;
  for (int i = threadIdx.x; i < dout; i += 256)
    orow[i] = ca*mr[i] + cb*bias[i];
}

// ---------- hyperbolic attention scores + softmax, one block per (b,h,i) ----------
__global__ __launch_bounds__(256) void attn_scores(const float* __restrict__ q,
                                                   const float* __restrict__ k,
                                                   const float* __restrict__ hs,
                                                   float* __restrict__ attn) {
  __shared__ float qs[DHEAD];
  __shared__ float sbuf[16];
  int idx = blockIdx.x;            // (b*NHEAD + h)*SEQ + i
  int i  = idx % SEQ;
  int bh = idx / SEQ;
  int h  = bh % NHEAD;
  int b  = bh / NHEAD;
  const float maxn = 1.0f - 1e-5f;   // max_norm = (1-1e-5)/sqrt(c), c=1
  const float* qr = q + ((size_t)(b*SEQ + i)*DMODEL) + h*DHEAD;
  if (threadIdx.x < DHEAD) qs[threadIdx.x] = fminf(qr[threadIdx.x], maxn);
  __syncthreads();
  float q2 = 0.f;
  #pragma unroll
  for (int d = 0; d < DHEAD; ++d) q2 += qs[d]*qs[d];
  int j = threadIdx.x;
  float sval = -1e30f;
  if (j < SEQ) {
    const float* kr = k + ((size_t)(b*SEQ + j)*DMODEL) + h*DHEAD;
    float kq = 0.f, k2 = 0.f;
    #pragma unroll
    for (int d = 0; d < DHEAD; ++d) {
      float kv = fminf(kr[d], maxn);
      kq += kv*qs[d]; k2 += kv*kv;
    }
    // diff = mobius_add(-k, q): x=-k, y=q, xy = -k.q
    float xy = -kq;
    float al = 1.f + 2.f*xy + q2;
    float be = 1.f - k2;
    float num2 = al*al*k2 + 2.f*al*be*xy + be*be*q2;
    float den  = fmaxf(1.f + 2.f*xy + k2*q2, 1e-15f);
    float dns  = num2/(den*den);                 // c * ||diff||^2
    float denom = (1.f - q2)*(1.f - k2) + 1e-15f;
    float arg = 1.f + 2.f*dns/denom;
    arg = fmaxf(arg, 1.f + 1e-7f);
    float dist = logf(arg + sqrtf(arg*arg - 1.f));
    sval = -dist / (hs[h] * 8.0f);               // sqrt(Dh)=8
  }
  // softmax over j
  float m = sval;
  #pragma unroll
  for (int off = 32; off; off >>= 1) m = fmaxf(m, __shfl_xor(m, off));
  int wid = threadIdx.x >> 6;
  if ((threadIdx.x & 63) == 0) sbuf[wid] = m;
  __syncthreads();
  m = fmaxf(fmaxf(sbuf[0], sbuf[1]), fmaxf(sbuf[2], sbuf[3]));
  __syncthreads();
  float e = (j < SEQ) ? expf(sval - m) : 0.f;
  float ssum = e;
  #pragma unroll
  for (int off = 32; off; off >>= 1) ssum += __shfl_xor(ssum, off);
  if ((threadIdx.x & 63) == 0) sbuf[wid] = ssum;
  __syncthreads();
  ssum = sbuf[0] + sbuf[1] + sbuf[2] + sbuf[3];
  if (j < SEQ) attn[(size_t)idx*SEQ + j] = e / ssum;
}

// ---------- logmap0 per 64-elem head-row (v layout (B,S,D) == rows of 64) ----------
__global__ __launch_bounds__(256) void logmap0_rows64(const float* __restrict__ v,
                                                      float* __restrict__ lv, int nrows) {
  int row = blockIdx.x*4 + (threadIdx.x >> 6);
  if (row >= nrows) return;
  int lane = threadIdx.x & 63;
  float vv = v[(size_t)row*64 + lane];
  float s2 = vv*vv;
  #pragma unroll
  for (int off = 32; off; off >>= 1) s2 += __shfl_xor(s2, off);
  float n = sqrtf(fmaxf(s2, 1e-15f));
  float scl = atanhf(fminf(n, 1.f - 1e-5f))/n;
  lv[(size_t)row*64 + lane] = scl*vv;
}

// ---------- PV: ao = expmap0(attn @ logv), one wave per (b,h,i) ----------
__global__ __launch_bounds__(64) void attn_pv(const float* __restrict__ attn,
                                              const float* __restrict__ lv,
                                              float* __restrict__ ao) {
  int idx = blockIdx.x;            // (b*NHEAD+h)*SEQ + i
  int i  = idx % SEQ;
  int bh = idx / SEQ;
  int h  = bh % NHEAD;
  int b  = bh / NHEAD;
  int lane = threadIdx.x;
  __shared__ float as[SEQ];
  const float* arow = attn + (size_t)idx*SEQ;
  for (int j = lane; j < SEQ; j += 64) as[j] = arow[j];
  __syncthreads();
  float acc = 0.f;
  const float* lvb = lv + ((size_t)(b*SEQ)*NHEAD + h)*64 + lane;
  for (int j = 0; j < SEQ; ++j) acc += as[j] * lvb[(size_t)j*DMODEL];
  float s2 = acc*acc;
  #pragma unroll
  for (int off = 32; off; off >>= 1) s2 += __shfl_xor(s2, off);
  float n = sqrtf(fmaxf(s2, 1e-15f));
  float scl = tanhf(n)/n;
  ao[((size_t)(b*SEQ + i)*NHEAD + h)*64 + lane] = scl*acc;
}

// ---------- residual (mobius_add(x, mobius_scalar_mul(beta,y))) + hyp_layer_norm ----------
__global__ __launch_bounds__(256) void resid_ln(const float* __restrict__ X,
                                                const float* __restrict__ Y,
                                                const float* __restrict__ betap,
                                                const float* __restrict__ lnw,
                                                const float* __restrict__ lnb,
                                                float* __restrict__ out) {
  __shared__ float sbuf[16];
  int r = blockIdx.x;
  const float* xr = X + (size_t)r*DMODEL;
  const float* yr = Y + (size_t)r*DMODEL;
  float xv[3], yv[3];
  float x2 = 0.f, yy = 0.f, xy = 0.f, dm = 0.f;
  #pragma unroll
  for (int l = 0; l < 3; ++l) {
    int i = threadIdx.x + l*256;
    xv[l] = xr[i]; yv[l] = yr[i];
    x2 += xv[l]*xv[l]; yy += yv[l]*yv[l]; xy += xv[l]*yv[l];
  }
  block_reduce_sum4(x2, yy, xy, dm, sbuf);
  // mobius_scalar_mul(beta, y)
  float beta = betap[0];
  float ny = sqrtf(fmaxf(yy, 1e-15f));
  float scs = tanhf(beta * atanhf(fminf(ny, 1.f - 1e-5f))) / ny;
  float y2  = scs*scs*yy;
  float xys = scs*xy;
  // mobius_add(x, ys)
  float den = fmaxf(1.f + 2.f*xys + x2*y2, 1e-15f);
  float ca = (1.f + 2.f*xys + y2)/den;
  float cb = (1.f - x2)*scs/den;
  float hv[3]; float h2 = 0.f;
  #pragma unroll
  for (int l = 0; l < 3; ++l) { hv[l] = ca*xv[l] + cb*yv[l]; h2 += hv[l]*hv[l]; }
  float z1 = 0.f, z2 = 0.f, z3 = 0.f;
  block_reduce_sum4(h2, z1, z2, z3, sbuf);
  // logmap0
  float nh = sqrtf(fmaxf(h2, 1e-15f));
  float scl = atanhf(fminf(nh, 1.f - 1e-5f))/nh;
  float tv[3]; float tsum = 0.f, tsq = 0.f;
  #pragma unroll
  for (int l = 0; l < 3; ++l) { tv[l] = scl*hv[l]; tsum += tv[l]; tsq += tv[l]*tv[l]; }
  float zz = 0.f, zw = 0.f;
  block_reduce_sum4(tsum, tsq, zz, zw, sbuf);
  float mu  = tsum * (1.f/768.f);
  float var = tsq * (1.f/768.f) - mu*mu;
  float rstd = rsqrtf(var + 1e-5f);
  // layer norm + expmap0
  float lnv[3]; float l2 = 0.f;
  #pragma unroll
  for (int l = 0; l < 3; ++l) {
    int i = threadIdx.x + l*256;
    lnv[l] = (tv[l] - mu)*rstd*lnw[i] + lnb[i];
    l2 += lnv[l]*lnv[l];
  }
  float w1 = 0.f, w2 = 0.f, w3 = 0.f;
  block_reduce_sum4(l2, w1, w2, w3, sbuf);
  float nl = sqrtf(fmaxf(l2, 1e-15f));
  float sce = tanhf(nl)/nl;
  #pragma unroll
  for (int l = 0; l < 3; ++l) {
    int i = threadIdx.x + l*256;
    out[(size_t)r*DMODEL + i] = sce*lnv[l];
  }
}

// ---------- mobius relu on FF rows (in place): expmap0(relu(logmap0(f))) ----------
__global__ __launch_bounds__(256) void mobius_relu(float* __restrict__ f) {
  __shared__ float sbuf[16];
  int r = blockIdx.x;
  float* fr = f + (size_t)r*DFF;
  float fv[12];
  float s2 = 0.f, z1 = 0.f, z2 = 0.f, z3 = 0.f;
  #pragma unroll
  for (int l = 0; l < 12; ++l) { fv[l] = fr[threadIdx.x + l*256]; s2 += fv[l]*fv[l]; }
  block_reduce_sum4(s2, z1, z2, z3, sbuf);
  float n = sqrtf(fmaxf(s2, 1e-15f));
  float scl = atanhf(fminf(n, 1.f - 1e-5f))/n;
  float rv[12]; float r2 = 0.f;
  #pragma unroll
  for (int l = 0; l < 12; ++l) { rv[l] = fmaxf(scl*fv[l], 0.f); r2 += rv[l]*rv[l]; }
  float w1 = 0.f, w2 = 0.f, w3 = 0.f;
  block_reduce_sum4(r2, w1, w2, w3, sbuf);
  float nr = sqrtf(fmaxf(r2, 1e-15f));
  float sce = tanhf(nr)/nr;
  #pragma unroll
  for (int l = 0; l < 12; ++l) fr[threadIdx.x + l*256] = sce*rv[l];
}

extern "C" void kernel_launch(void* const* d_in, const int* in_sizes, int n_in,
                              void* d_out, int out_size, void* d_ws, size_t ws_size,
                              hipStream_t stream) {
  const float* x    = (const float*)d_in[0];
  const float* wq   = (const float*)d_in[1];
  const float* bq   = (const float*)d_in[2];
  const float* wk   = (const float*)d_in[3];
  const float* bk   = (const float*)d_in[4];
  const float* wv   = (const float*)d_in[5];
  const float* bv   = (const float*)d_in[6];
  const float* wo   = (const float*)d_in[7];
  const float* bo   = (const float*)d_in[8];
  const float* hs   = (const float*)d_in[9];
  const float* w1   = (const float*)d_in[10];
  const float* b1   = (const float*)d_in[11];
  const float* w2   = (const float*)d_in[12];
  const float* b2   = (const float*)d_in[13];
  const float* beta = (const float*)d_in[14];
  const float* ln1w = (const float*)d_in[15];
  const float* ln1b = (const float*)d_in[16];
  const float* ln2w = (const float*)d_in[17];
  const float* ln2b = (const float*)d_in[18];
  float* out = (float*)d_out;

  float* ws = (float*)d_ws;
  size_t off = 0;
  auto alloc = [&](size_t n) { float* p = ws + off; off += n; return p; };
  float* tmp  = alloc((size_t)NROWS*DFF);      // raw GEMM output (reused)
  float* fbuf = alloc((size_t)NROWS*DFF);      // FFN intermediate
  float* qb   = alloc((size_t)NROWS*DMODEL);
  float* kb   = alloc((size_t)NROWS*DMODEL);
  float* vb   = alloc((size_t)NROWS*DMODEL);
  float* lv   = alloc((size_t)NROWS*DMODEL);
  float* attn = alloc((size_t)BATCH*NHEAD*SEQ*SEQ);
  float* ao   = alloc((size_t)NROWS*DMODEL);
  float* aop  = alloc((size_t)NROWS*DMODEL);
  float* hb   = alloc((size_t)NROWS*DMODEL);
  float* f2   = alloc((size_t)NROWS*DMODEL);

  dim3 blk(256);
  dim3 gD(DMODEL/64, (NROWS+63)/64);   // 12 x 7
  dim3 gF(DFF/64,   (NROWS+63)/64);    // 48 x 7

  // Q, K, V projections
  gemm_xwt<<<gD, blk, 0, stream>>>(x, wq, tmp, NROWS, DMODEL, DMODEL);
  hyp_linear_post<<<NROWS, blk, 0, stream>>>(x, tmp, bq, qb, DMODEL, DMODEL);
  gemm_xwt<<<gD, blk, 0, stream>>>(x, wk, tmp, NROWS, DMODEL, DMODEL);
  hyp_linear_post<<<NROWS, blk, 0, stream>>>(x, tmp, bk, kb, DMODEL, DMODEL);
  gemm_xwt<<<gD, blk, 0, stream>>>(x, wv, tmp, NROWS, DMODEL, DMODEL);
  hyp_linear_post<<<NROWS, blk, 0, stream>>>(x, tmp, bv, vb, DMODEL, DMODEL);

  // attention
  attn_scores<<<BATCH*NHEAD*SEQ, blk, 0, stream>>>(qb, kb, hs, attn);
  logmap0_rows64<<<(NHROWS+3)/4, blk, 0, stream>>>(vb, lv, NHROWS);
  attn_pv<<<BATCH*NHEAD*SEQ, dim3(64), 0, stream>>>(attn, lv, ao);

  // output projection
  gemm_xwt<<<gD, blk, 0, stream>>>(ao, wo, tmp, NROWS, DMODEL, DMODEL);
  hyp_linear_post<<<NROWS, blk, 0, stream>>>(ao, tmp, bo, aop, DMODEL, DMODEL);

  // residual 1 + hyp layer norm
  resid_ln<<<NROWS, blk, 0, stream>>>(x, aop, beta, ln1w, ln1b, hb);

  // FFN
  gemm_xwt<<<gF, blk, 0, stream>>>(hb, w1, tmp, NROWS, DMODEL, DFF);
  hyp_linear_post<<<NROWS, blk, 0, stream>>>(hb, tmp, b1, fbuf, DMODEL, DFF);
  mobius_relu<<<NROWS, blk, 0, stream>>>(fbuf);
  gemm_xwt<<<gD, blk, 0, stream>>>(fbuf, w2, tmp, NROWS, DFF, DMODEL);
  hyp_linear_post<<<NROWS, blk, 0, stream>>>(fbuf, tmp, b2, f2, DFF, DMODEL);

  // residual 2 + hyp layer norm -> out
  resid_ln<<<NROWS, blk, 0, stream>>>(hb, f2, beta, ln2w, ln2b, out);
}

// Round 3
// 218.030 us; speedup vs baseline: 3.6799x; 3.6799x over previous
//
#include <hip/hip_runtime.h>
#include <hip/hip_bf16.h>
#include <math.h>

#define BATCH 2
#define SEQ 196
#define DMODEL 768
#define NHEAD 12
#define DHEAD 64
#define DFF 3072
#define NROWS (BATCH*SEQ)        // 392
#define NHROWS (NROWS*NHEAD)     // 4704

typedef __attribute__((ext_vector_type(8))) short short8;
typedef __attribute__((ext_vector_type(4))) float f32x4;

// ---------- utilities ----------
__device__ __forceinline__ short f2bf(float f) {
  unsigned u = __builtin_bit_cast(unsigned, f);
  u += 0x7FFFu + ((u >> 16) & 1u);      // round-to-nearest-even
  return (short)(u >> 16);
}

__device__ __forceinline__ void block_reduce_sum4(float& a, float& b, float& c, float& d,
                                                  float* sbuf /*>=16 floats*/) {
  #pragma unroll
  for (int off = 32; off; off >>= 1) {
    a += __shfl_xor(a, off);
    b += __shfl_xor(b, off);
    c += __shfl_xor(c, off);
    d += __shfl_xor(d, off);
  }
  int wid = threadIdx.x >> 6;
  if ((threadIdx.x & 63) == 0) {
    sbuf[wid*4+0] = a; sbuf[wid*4+1] = b; sbuf[wid*4+2] = c; sbuf[wid*4+3] = d;
  }
  __syncthreads();
  a = sbuf[0] + sbuf[4] + sbuf[8]  + sbuf[12];
  b = sbuf[1] + sbuf[5] + sbuf[9]  + sbuf[13];
  c = sbuf[2] + sbuf[6] + sbuf[10] + sbuf[14];
  d = sbuf[3] + sbuf[7] + sbuf[11] + sbuf[15];
  __syncthreads();
}

// ---------- bf16 MFMA GEMM: Y[n][m] = X[n][K] @ W[m][K]^T (f32 in/out) ----------
// 64x64 tile, 4 waves (2x2), each wave 32x32 via 2x2 frags of 16x16, K-step 32.
// blockIdx.z selects (W,Y) among up to 3 for QKV fusion.
#define LPITCH 40   // bf16 elems per LDS row (32 + 8 pad) -> 80B stride, 2-way start banks
__global__ __launch_bounds__(256) void gemm_bf16_xwt(
    const float* __restrict__ X,
    const float* __restrict__ W1, const float* __restrict__ W2, const float* __restrict__ W3,
    float* __restrict__ Y1, float* __restrict__ Y2, float* __restrict__ Y3,
    int n, int K, int m) {
  const float* W = W1; float* Y = Y1;
  if (blockIdx.z == 1) { W = W2; Y = Y2; }
  else if (blockIdx.z == 2) { W = W3; Y = Y3; }

  __shared__ short As[64*LPITCH];
  __shared__ short Bs[64*LPITCH];
  const int tid  = threadIdx.x;
  const int lane = tid & 63;
  const int w    = tid >> 6, wr = w >> 1, wc = w & 1;
  const int brow = blockIdx.y * 64, bcol = blockIdx.x * 64;

  // staging role: thread loads 8 consecutive f32 of one row
  const int sr = tid >> 2, skb = (tid & 3) * 8;
  const int gr = brow + sr;
  const bool rok = gr < n;
  const float* xp = X + (size_t)gr * K + skb;
  const float* wp = W + (size_t)(bcol + sr) * K + skb;

  f32x4 acc[2][2] = {};
  const int kgo = (lane >> 4) * 8;           // k offset within 32-wide K-step
  const int arow0 = (wr*32 + (lane & 15)) * LPITCH + kgo;
  const int brow0 = (wc*32 + (lane & 15)) * LPITCH + kgo;

  for (int k0 = 0; k0 < K; k0 += 32) {
    float xv[8], wv[8];
    if (rok) {
      *(f32x4*)&xv[0] = *(const f32x4*)(xp + k0);
      *(f32x4*)&xv[4] = *(const f32x4*)(xp + k0 + 4);
    } else {
      #pragma unroll
      for (int i = 0; i < 8; ++i) xv[i] = 0.f;
    }
    *(f32x4*)&wv[0] = *(const f32x4*)(wp + k0);
    *(f32x4*)&wv[4] = *(const f32x4*)(wp + k0 + 4);
    short8 xa, wa;
    #pragma unroll
    for (int i = 0; i < 8; ++i) { xa[i] = f2bf(xv[i]); wa[i] = f2bf(wv[i]); }
    __syncthreads();   // prior iteration's reads done before overwrite
    *(short8*)&As[sr*LPITCH + skb] = xa;
    *(short8*)&Bs[sr*LPITCH + skb] = wa;
    __syncthreads();

    short8 af0 = *(const short8*)&As[arow0];
    short8 af1 = *(const short8*)&As[arow0 + 16*LPITCH];
    short8 bf0 = *(const short8*)&Bs[brow0];
    short8 bf1 = *(const short8*)&Bs[brow0 + 16*LPITCH];
    acc[0][0] = __builtin_amdgcn_mfma_f32_16x16x32_bf16(af0, bf0, acc[0][0], 0, 0, 0);
    acc[0][1] = __builtin_amdgcn_mfma_f32_16x16x32_bf16(af0, bf1, acc[0][1], 0, 0, 0);
    acc[1][0] = __builtin_amdgcn_mfma_f32_16x16x32_bf16(af1, bf0, acc[1][0], 0, 0, 0);
    acc[1][1] = __builtin_amdgcn_mfma_f32_16x16x32_bf16(af1, bf1, acc[1][1], 0, 0, 0);
  }

  // C/D: col = lane&15, row = (lane>>4)*4 + j  (m89-verified)
  const int ccol = bcol + wc*32 + (lane & 15);
  #pragma unroll
  for (int mr = 0; mr < 2; ++mr) {
    #pragma unroll
    for (int j = 0; j < 4; ++j) {
      int grow = brow + wr*32 + mr*16 + (lane >> 4)*4 + j;
      if (grow < n) {
        float* yr = Y + (size_t)grow * m + ccol;
        yr[0]  = acc[mr][0][j];
        yr[16] = acc[mr][1][j];
      }
    }
  }
}

// ---------- hyp_linear post row: out = mobius_add(matvec_scale(MX), bias) ----------
__device__ __forceinline__ void hyp_post_row(const float* __restrict__ xr,
                                             const float* __restrict__ mr,
                                             const float* __restrict__ bias,
                                             float* __restrict__ orow,
                                             int din, int dout, float* sbuf) {
  float xs = 0.f, ms = 0.f, mb = 0.f, bb = 0.f;
  for (int i = threadIdx.x; i < din; i += 256) { float v = xr[i]; xs += v*v; }
  for (int i = threadIdx.x; i < dout; i += 256) {
    float v = mr[i], b = bias[i];
    ms += v*v; mb += v*b; bb += b*b;
  }
  block_reduce_sum4(xs, ms, mb, bb, sbuf);
  float xn  = sqrtf(fmaxf(xs, 1e-15f));
  float mxn = sqrtf(fmaxf(ms, 1e-15f));
  float art = atanhf(fminf(xn, 1.f - 1e-5f));
  float scm = tanhf(mxn/xn*art)/mxn;
  float x2 = scm*scm*ms;
  float y2 = bb;
  float xy = scm*mb;
  float den = fmaxf(1.f + 2.f*xy + x2*y2, 1e-15f);
  float ca = (1.f + 2.f*xy + y2) * scm / den;
  float cb = (1.f - x2) / den;
  for (int i = threadIdx.x; i < dout; i += 256)
    orow[i] = ca*mr[i] + cb*bias[i];
}

__global__ __launch_bounds__(256) void hyp_linear_post(const float* __restrict__ X,
                                                       const float* __restrict__ MX,
                                                       const float* __restrict__ bias,
                                                       float* __restrict__ out,
                                                       int din, int dout) {
  __shared__ float sbuf[16];
  int r = blockIdx.x;
  hyp_post_row(X + (size_t)r*din, MX + (size_t)r*dout, bias, out + (size_t)r*dout,
               din, dout, sbuf);
}

// fused QKV post: blockIdx.y = 0/1/2 -> q/k/v
__global__ __launch_bounds__(256) void qkv_post(const float* __restrict__ X,
                                                const float* __restrict__ MQ,
                                                const float* __restrict__ MK,
                                                const float* __restrict__ MV,
                                                const float* __restrict__ bq,
                                                const float* __restrict__ bk,
                                                const float* __restrict__ bv,
                                                float* __restrict__ oq,
                                                float* __restrict__ ok,
                                                float* __restrict__ ov) {
  __shared__ float sbuf[16];
  int r = blockIdx.x;
  const float* MX = MQ; const float* b = bq; float* o = oq;
  if (blockIdx.y == 1) { MX = MK; b = bk; o = ok; }
  else if (blockIdx.y == 2) { MX = MV; b = bv; o = ov; }
  hyp_post_row(X + (size_t)r*DMODEL, MX + (size_t)r*DMODEL, b, o + (size_t)r*DMODEL,
               DMODEL, DMODEL, sbuf);
}

// ---------- hyperbolic attention scores + softmax, one block per (b,h,i) ----------
__global__ __launch_bounds__(256) void attn_scores(const float* __restrict__ q,
                                                   const float* __restrict__ k,
                                                   const float* __restrict__ hs,
                                                   float* __restrict__ attn) {
  __shared__ float qs[DHEAD];
  __shared__ float sbuf[16];
  int idx = blockIdx.x;            // (b*NHEAD + h)*SEQ + i
  int i  = idx % SEQ;
  int bh = idx / SEQ;
  int h  = bh % NHEAD;
  int b  = bh / NHEAD;
  const float maxn = 1.0f - 1e-5f;
  const float* qr = q + ((size_t)(b*SEQ + i)*DMODEL) + h*DHEAD;
  if (threadIdx.x < DHEAD) qs[threadIdx.x] = fminf(qr[threadIdx.x], maxn);
  __syncthreads();
  float q2 = 0.f;
  #pragma unroll
  for (int d = 0; d < DHEAD; ++d) q2 += qs[d]*qs[d];
  int j = threadIdx.x;
  float sval = -1e30f;
  if (j < SEQ) {
    const float* kr = k + ((size_t)(b*SEQ + j)*DMODEL) + h*DHEAD;
    float kq = 0.f, k2 = 0.f;
    #pragma unroll
    for (int d = 0; d < DHEAD; ++d) {
      float kv = fminf(kr[d], maxn);
      kq += kv*qs[d]; k2 += kv*kv;
    }
    float xy = -kq;
    float al = 1.f + 2.f*xy + q2;
    float be = 1.f - k2;
    float num2 = al*al*k2 + 2.f*al*be*xy + be*be*q2;
    float den  = fmaxf(1.f + 2.f*xy + k2*q2, 1e-15f);
    float dns  = num2/(den*den);
    float denom = (1.f - q2)*(1.f - k2) + 1e-15f;
    float arg = 1.f + 2.f*dns/denom;
    arg = fmaxf(arg, 1.f + 1e-7f);
    float dist = logf(arg + sqrtf(arg*arg - 1.f));
    sval = -dist / (hs[h] * 8.0f);
  }
  float m = sval;
  #pragma unroll
  for (int off = 32; off; off >>= 1) m = fmaxf(m, __shfl_xor(m, off));
  int wid = threadIdx.x >> 6;
  if ((threadIdx.x & 63) == 0) sbuf[wid] = m;
  __syncthreads();
  m = fmaxf(fmaxf(sbuf[0], sbuf[1]), fmaxf(sbuf[2], sbuf[3]));
  __syncthreads();
  float e = (j < SEQ) ? expf(sval - m) : 0.f;
  float ssum = e;
  #pragma unroll
  for (int off = 32; off; off >>= 1) ssum += __shfl_xor(ssum, off);
  if ((threadIdx.x & 63) == 0) sbuf[wid] = ssum;
  __syncthreads();
  ssum = sbuf[0] + sbuf[1] + sbuf[2] + sbuf[3];
  if (j < SEQ) attn[(size_t)idx*SEQ + j] = e / ssum;
}

// ---------- logmap0 per 64-elem head-row ----------
__global__ __launch_bounds__(256) void logmap0_rows64(const float* __restrict__ v,
                                                      float* __restrict__ lv, int nrows) {
  int row = blockIdx.x*4 + (threadIdx.x >> 6);
  if (row >= nrows) return;
  int lane = threadIdx.x & 63;
  float vv = v[(size_t)row*64 + lane];
  float s2 = vv*vv;
  #pragma unroll
  for (int off = 32; off; off >>= 1) s2 += __shfl_xor(s2, off);
  float n = sqrtf(fmaxf(s2, 1e-15f));
  float scl = atanhf(fminf(n, 1.f - 1e-5f))/n;
  lv[(size_t)row*64 + lane] = scl*vv;
}

// ---------- PV: ao = expmap0(attn @ logv), one wave per (b,h,i) ----------
__global__ __launch_bounds__(64) void attn_pv(const float* __restrict__ attn,
                                              const float* __restrict__ lv,
                                              float* __restrict__ ao) {
  int idx = blockIdx.x;
  int i  = idx % SEQ;
  int bh = idx / SEQ;
  int h  = bh % NHEAD;
  int b  = bh / NHEAD;
  int lane = threadIdx.x;
  __shared__ float as[SEQ];
  const float* arow = attn + (size_t)idx*SEQ;
  for (int j = lane; j < SEQ; j += 64) as[j] = arow[j];
  __syncthreads();
  float acc = 0.f;
  const float* lvb = lv + ((size_t)(b*SEQ)*NHEAD + h)*64 + lane;
  for (int j = 0; j < SEQ; ++j) acc += as[j] * lvb[(size_t)j*DMODEL];
  float s2 = acc*acc;
  #pragma unroll
  for (int off = 32; off; off >>= 1) s2 += __shfl_xor(s2, off);
  float n = sqrtf(fmaxf(s2, 1e-15f));
  float scl = tanhf(n)/n;
  ao[((size_t)(b*SEQ + i)*NHEAD + h)*64 + lane] = scl*acc;
}

// ---------- residual + hyp layer norm ----------
__global__ __launch_bounds__(256) void resid_ln(const float* __restrict__ X,
                                                const float* __restrict__ Y,
                                                const float* __restrict__ betap,
                                                const float* __restrict__ lnw,
                                                const float* __restrict__ lnb,
                                                float* __restrict__ out) {
  __shared__ float sbuf[16];
  int r = blockIdx.x;
  const float* xr = X + (size_t)r*DMODEL;
  const float* yr = Y + (size_t)r*DMODEL;
  float xv[3], yv[3];
  float x2 = 0.f, yy = 0.f, xy = 0.f, dm = 0.f;
  #pragma unroll
  for (int l = 0; l < 3; ++l) {
    int i = threadIdx.x + l*256;
    xv[l] = xr[i]; yv[l] = yr[i];
    x2 += xv[l]*xv[l]; yy += yv[l]*yv[l]; xy += xv[l]*yv[l];
  }
  block_reduce_sum4(x2, yy, xy, dm, sbuf);
  float beta = betap[0];
  float ny = sqrtf(fmaxf(yy, 1e-15f));
  float scs = tanhf(beta * atanhf(fminf(ny, 1.f - 1e-5f))) / ny;
  float y2  = scs*scs*yy;
  float xys = scs*xy;
  float den = fmaxf(1.f + 2.f*xys + x2*y2, 1e-15f);
  float ca = (1.f + 2.f*xys + y2)/den;
  float cb = (1.f - x2)*scs/den;
  float hv[3]; float h2 = 0.f;
  #pragma unroll
  for (int l = 0; l < 3; ++l) { hv[l] = ca*xv[l] + cb*yv[l]; h2 += hv[l]*hv[l]; }
  float z1 = 0.f, z2 = 0.f, z3 = 0.f;
  block_reduce_sum4(h2, z1, z2, z3, sbuf);
  float nh = sqrtf(fmaxf(h2, 1e-15f));
  float scl = atanhf(fminf(nh, 1.f - 1e-5f))/nh;
  float tv[3]; float tsum = 0.f, tsq = 0.f;
  #pragma unroll
  for (int l = 0; l < 3; ++l) { tv[l] = scl*hv[l]; tsum += tv[l]; tsq += tv[l]*tv[l]; }
  float zz = 0.f, zw = 0.f;
  block_reduce_sum4(tsum, tsq, zz, zw, sbuf);
  float mu  = tsum * (1.f/768.f);
  float var = tsq * (1.f/768.f) - mu*mu;
  float rstd = rsqrtf(var + 1e-5f);
  float lnv[3]; float l2 = 0.f;
  #pragma unroll
  for (int l = 0; l < 3; ++l) {
    int i = threadIdx.x + l*256;
    lnv[l] = (tv[l] - mu)*rstd*lnw[i] + lnb[i];
    l2 += lnv[l]*lnv[l];
  }
  float w1 = 0.f, w2 = 0.f, w3 = 0.f;
  block_reduce_sum4(l2, w1, w2, w3, sbuf);
  float nl = sqrtf(fmaxf(l2, 1e-15f));
  float sce = tanhf(nl)/nl;
  #pragma unroll
  for (int l = 0; l < 3; ++l) {
    int i = threadIdx.x + l*256;
    out[(size_t)r*DMODEL + i] = sce*lnv[l];
  }
}

// ---------- mobius relu on FF rows (in place) ----------
__global__ __launch_bounds__(256) void mobius_relu(float* __restrict__ f) {
  __shared__ float sbuf[16];
  int r = blockIdx.x;
  float* fr = f + (size_t)r*DFF;
  float fv[12];
  float s2 = 0.f, z1 = 0.f, z2 = 0.f, z3 = 0.f;
  #pragma unroll
  for (int l = 0; l < 12; ++l) { fv[l] = fr[threadIdx.x + l*256]; s2 += fv[l]*fv[l]; }
  block_reduce_sum4(s2, z1, z2, z3, sbuf);
  float n = sqrtf(fmaxf(s2, 1e-15f));
  float scl = atanhf(fminf(n, 1.f - 1e-5f))/n;
  float rv[12]; float r2 = 0.f;
  #pragma unroll
  for (int l = 0; l < 12; ++l) { rv[l] = fmaxf(scl*fv[l], 0.f); r2 += rv[l]*rv[l]; }
  float w1 = 0.f, w2 = 0.f, w3 = 0.f;
  block_reduce_sum4(r2, w1, w2, w3, sbuf);
  float nr = sqrtf(fmaxf(r2, 1e-15f));
  float sce = tanhf(nr)/nr;
  #pragma unroll
  for (int l = 0; l < 12; ++l) fr[threadIdx.x + l*256] = sce*rv[l];
}

extern "C" void kernel_launch(void* const* d_in, const int* in_sizes, int n_in,
                              void* d_out, int out_size, void* d_ws, size_t ws_size,
                              hipStream_t stream) {
  const float* x    = (const float*)d_in[0];
  const float* wq   = (const float*)d_in[1];
  const float* bq   = (const float*)d_in[2];
  const float* wk   = (const float*)d_in[3];
  const float* bk   = (const float*)d_in[4];
  const float* wv   = (const float*)d_in[5];
  const float* bv   = (const float*)d_in[6];
  const float* wo   = (const float*)d_in[7];
  const float* bo   = (const float*)d_in[8];
  const float* hs   = (const float*)d_in[9];
  const float* w1   = (const float*)d_in[10];
  const float* b1   = (const float*)d_in[11];
  const float* w2   = (const float*)d_in[12];
  const float* b2   = (const float*)d_in[13];
  const float* beta = (const float*)d_in[14];
  const float* ln1w = (const float*)d_in[15];
  const float* ln1b = (const float*)d_in[16];
  const float* ln2w = (const float*)d_in[17];
  const float* ln2b = (const float*)d_in[18];
  float* out = (float*)d_out;

  float* ws = (float*)d_ws;
  size_t off = 0;
  auto alloc = [&](size_t n) { float* p = ws + off; off += n; return p; };
  float* tq   = alloc((size_t)NROWS*DMODEL);   // raw QKV gemm out; later reused as tmp
  float* tk   = alloc((size_t)NROWS*DMODEL);   // later: aop
  float* tv   = alloc((size_t)NROWS*DMODEL);   // later: f2
  float* qb   = alloc((size_t)NROWS*DMODEL);
  float* kb   = alloc((size_t)NROWS*DMODEL);
  float* vb   = alloc((size_t)NROWS*DMODEL);
  float* lv   = alloc((size_t)NROWS*DMODEL);
  float* attn = alloc((size_t)BATCH*NHEAD*SEQ*SEQ);
  float* ao   = alloc((size_t)NROWS*DMODEL);
  float* hb   = alloc((size_t)NROWS*DMODEL);
  float* tmpF = alloc((size_t)NROWS*DFF);
  float* fbuf = alloc((size_t)NROWS*DFF);

  dim3 blk(256);
  dim3 gQKV(DMODEL/64, (NROWS+63)/64, 3);   // 12 x 7 x 3
  dim3 gD(DMODEL/64,  (NROWS+63)/64, 1);    // 12 x 7
  dim3 gF(DFF/64,     (NROWS+63)/64, 1);    // 48 x 7

  // QKV projections (fused GEMM + fused post)
  gemm_bf16_xwt<<<gQKV, blk, 0, stream>>>(x, wq, wk, wv, tq, tk, tv, NROWS, DMODEL, DMODEL);
  qkv_post<<<dim3(NROWS,3), blk, 0, stream>>>(x, tq, tk, tv, bq, bk, bv, qb, kb, vb);

  // attention
  attn_scores<<<BATCH*NHEAD*SEQ, blk, 0, stream>>>(qb, kb, hs, attn);
  logmap0_rows64<<<(NHROWS+3)/4, blk, 0, stream>>>(vb, lv, NHROWS);
  attn_pv<<<BATCH*NHEAD*SEQ, dim3(64), 0, stream>>>(attn, lv, ao);

  // output projection (tq reused as tmp, tk as aop)
  gemm_bf16_xwt<<<gD, blk, 0, stream>>>(ao, wo, wo, wo, tq, tq, tq, NROWS, DMODEL, DMODEL);
  hyp_linear_post<<<NROWS, blk, 0, stream>>>(ao, tq, bo, tk, DMODEL, DMODEL);

  // residual 1 + hyp layer norm
  resid_ln<<<NROWS, blk, 0, stream>>>(x, tk, beta, ln1w, ln1b, hb);

  // FFN
  gemm_bf16_xwt<<<gF, blk, 0, stream>>>(hb, w1, w1, w1, tmpF, tmpF, tmpF, NROWS, DMODEL, DFF);
  hyp_linear_post<<<NROWS, blk, 0, stream>>>(hb, tmpF, b1, fbuf, DMODEL, DFF);
  mobius_relu<<<NROWS, blk, 0, stream>>>(fbuf);
  gemm_bf16_xwt<<<gD, blk, 0, stream>>>(fbuf, w2, w2, w2, tq, tq, tq, NROWS, DFF, DMODEL);
  hyp_linear_post<<<NROWS, blk, 0, stream>>>(fbuf, tq, b2, tv, DFF, DMODEL);

  // residual 2 + hyp layer norm -> out
  resid_ln<<<NROWS, blk, 0, stream>>>(hb, tv, beta, ln2w, ln2b, out);
}

// Round 5
// 166.281 us; speedup vs baseline: 4.8251x; 1.3112x over previous
//
#include <hip/hip_runtime.h>
#include <hip/hip_bf16.h>
#include <math.h>

#define BATCH 2
#define SEQ 196
#define DMODEL 768
#define NHEAD 12
#define DHEAD 64
#define DFF 3072
#define NROWS (BATCH*SEQ)        // 392
#define NHROWS (NROWS*NHEAD)     // 4704

typedef __attribute__((ext_vector_type(8))) short short8;
typedef __attribute__((ext_vector_type(4))) float f32x4;

// bf16 scratch layout (element offsets within the bf16 pool)
#define XB_OFF   0
#define XB_LEN   (NROWS*DMODEL)            // 301056
#define WQ_OFF   (XB_OFF + XB_LEN)
#define WD_LEN   (DMODEL*DMODEL)           // 589824
#define WK_OFF   (WQ_OFF + WD_LEN)
#define WV_OFF   (WK_OFF + WD_LEN)
#define WO_OFF   (WV_OFF + WD_LEN)
#define W1_OFF   (WO_OFF + WD_LEN)
#define WF_LEN   (DFF*DMODEL)              // 2359296
#define W2_OFF   (W1_OFF + WF_LEN)
#define BF_TOTAL (W2_OFF + WF_LEN)         // 7378944 elems

// ---------- utilities ----------
__device__ __forceinline__ short f2bf(float f) {
  unsigned u = __builtin_bit_cast(unsigned, f);
  u += 0x7FFFu + ((u >> 16) & 1u);      // round-to-nearest-even
  return (short)(u >> 16);
}

__device__ __forceinline__ void block_reduce_sum4(float& a, float& b, float& c, float& d,
                                                  float* sbuf /*>=16 floats*/) {
  #pragma unroll
  for (int off = 32; off; off >>= 1) {
    a += __shfl_xor(a, off);
    b += __shfl_xor(b, off);
    c += __shfl_xor(c, off);
    d += __shfl_xor(d, off);
  }
  int wid = threadIdx.x >> 6;
  if ((threadIdx.x & 63) == 0) {
    sbuf[wid*4+0] = a; sbuf[wid*4+1] = b; sbuf[wid*4+2] = c; sbuf[wid*4+3] = d;
  }
  __syncthreads();
  a = sbuf[0] + sbuf[4] + sbuf[8]  + sbuf[12];
  b = sbuf[1] + sbuf[5] + sbuf[9]  + sbuf[13];
  c = sbuf[2] + sbuf[6] + sbuf[10] + sbuf[14];
  d = sbuf[3] + sbuf[7] + sbuf[11] + sbuf[15];
  __syncthreads();
}

// ---------- convert f32 -> bf16 pool (x + 6 weight matrices) ----------
__global__ __launch_bounds__(256) void cvt_bf16(
    const float* __restrict__ x,  const float* __restrict__ wq,
    const float* __restrict__ wk, const float* __restrict__ wv,
    const float* __restrict__ wo, const float* __restrict__ w1,
    const float* __restrict__ w2, short* __restrict__ d) {
  const float* s; size_t n, o;
  switch (blockIdx.y) {
    case 0: s = x;  n = XB_LEN; o = XB_OFF; break;
    case 1: s = wq; n = WD_LEN; o = WQ_OFF; break;
    case 2: s = wk; n = WD_LEN; o = WK_OFF; break;
    case 3: s = wv; n = WD_LEN; o = WV_OFF; break;
    case 4: s = wo; n = WD_LEN; o = WO_OFF; break;
    case 5: s = w1; n = WF_LEN; o = W1_OFF; break;
    default: s = w2; n = WF_LEN; o = W2_OFF; break;
  }
  size_t units = n >> 3;
  for (size_t u = (size_t)blockIdx.x*256 + threadIdx.x; u < units; u += (size_t)gridDim.x*256) {
    const f32x4* sp = (const f32x4*)(s + u*8);
    f32x4 v0 = sp[0], v1 = sp[1];
    short8 r;
    #pragma unroll
    for (int j = 0; j < 4; ++j) { r[j] = f2bf(v0[j]); r[j+4] = f2bf(v1[j]); }
    *(short8*)(d + o + u*8) = r;
  }
}

// ---------- bf16 MFMA GEMM: Y[n][m] = X[n][K] @ W[m][K]^T (bf16 in, f32 out) ----------
// 64x64 tile, 4 waves (2x2), K-step 64, register prefetch of next K-tile.
#define PITCH 72   // bf16 elems per LDS row (144B = 16B aligned; frag reads 2-way = free)
__global__ __launch_bounds__(256) void gemm_bf16(
    const short* __restrict__ X,
    const short* __restrict__ W1p, const short* __restrict__ W2p, const short* __restrict__ W3p,
    float* __restrict__ Y1, float* __restrict__ Y2, float* __restrict__ Y3,
    int n, int K, int m) {
  const short* W = W1p; float* Y = Y1;
  if (blockIdx.z == 1) { W = W2p; Y = Y2; }
  else if (blockIdx.z == 2) { W = W3p; Y = Y3; }

  __shared__ short As[64*PITCH];
  __shared__ short Bs[64*PITCH];
  const int tid  = threadIdx.x;
  const int lane = tid & 63;
  const int w    = tid >> 6, wr = w >> 1, wc = w & 1;
  const int brow = blockIdx.y * 64, bcol = blockIdx.x * 64;

  // staging: thread covers row sr, 32B (16 bf16) starting at col sc
  const int sr = tid >> 2, sc = (tid & 3) * 16;
  const bool rok = (brow + sr) < n;
  const short* xp = X + (size_t)(brow + sr) * K + sc;
  const short* wp = W + (size_t)(bcol + sr) * K + sc;

  f32x4 acc[2][2] = {};
  const int kgo = (lane >> 4) * 8;
  const short8 zero8 = {0,0,0,0,0,0,0,0};

  short8 xa0, xa1, wa0, wa1;
  if (rok) { xa0 = *(const short8*)(xp); xa1 = *(const short8*)(xp + 8); }
  else     { xa0 = zero8; xa1 = zero8; }
  wa0 = *(const short8*)(wp); wa1 = *(const short8*)(wp + 8);

  const int T = K / 64;
  for (int t = 0; t < T; ++t) {
    short8 xn0, xn1, wn0, wn1;
    const int kn = (t + 1 < T) ? (t + 1) * 64 : 0;   // last iter: dummy reload of k=0
    if (rok) { xn0 = *(const short8*)(xp + kn); xn1 = *(const short8*)(xp + kn + 8); }
    else     { xn0 = zero8; xn1 = zero8; }
    wn0 = *(const short8*)(wp + kn); wn1 = *(const short8*)(wp + kn + 8);

    __syncthreads();   // prior iteration's frag reads done
    *(short8*)&As[sr*PITCH + sc]     = xa0;
    *(short8*)&As[sr*PITCH + sc + 8] = xa1;
    *(short8*)&Bs[sr*PITCH + sc]     = wa0;
    *(short8*)&Bs[sr*PITCH + sc + 8] = wa1;
    __syncthreads();

    #pragma unroll
    for (int kk = 0; kk < 2; ++kk) {
      short8 a0 = *(const short8*)&As[(wr*32      + (lane & 15))*PITCH + kk*32 + kgo];
      short8 a1 = *(const short8*)&As[(wr*32 + 16 + (lane & 15))*PITCH + kk*32 + kgo];
      short8 b0 = *(const short8*)&Bs[(wc*32      + (lane & 15))*PITCH + kk*32 + kgo];
      short8 b1 = *(const short8*)&Bs[(wc*32 + 16 + (lane & 15))*PITCH + kk*32 + kgo];
      acc[0][0] = __builtin_amdgcn_mfma_f32_16x16x32_bf16(a0, b0, acc[0][0], 0, 0, 0);
      acc[0][1] = __builtin_amdgcn_mfma_f32_16x16x32_bf16(a0, b1, acc[0][1], 0, 0, 0);
      acc[1][0] = __builtin_amdgcn_mfma_f32_16x16x32_bf16(a1, b0, acc[1][0], 0, 0, 0);
      acc[1][1] = __builtin_amdgcn_mfma_f32_16x16x32_bf16(a1, b1, acc[1][1], 0, 0, 0);
    }
    xa0 = xn0; xa1 = xn1; wa0 = wn0; wa1 = wn1;
  }

  // C/D: col = lane&15, row = (lane>>4)*4 + j  (m89-verified)
  const int ccol = bcol + wc*32 + (lane & 15);
  #pragma unroll
  for (int mr = 0; mr < 2; ++mr) {
    #pragma unroll
    for (int j = 0; j < 4; ++j) {
      int grow = brow + wr*32 + mr*16 + (lane >> 4)*4 + j;
      if (grow < n) {
        float* yr = Y + (size_t)grow * m + ccol;
        yr[0]  = acc[mr][0][j];
        yr[16] = acc[mr][1][j];
      }
    }
  }
}

// ---------- hyp_linear post row ----------
__device__ __forceinline__ void hyp_post_row(const float* __restrict__ xr,
                                             const float* __restrict__ mr,
                                             const float* __restrict__ bias,
                                             float* __restrict__ orow,
                                             int din, int dout, float* sbuf) {
  float xs = 0.f, ms = 0.f, mb = 0.f, bb = 0.f;
  for (int i = threadIdx.x; i < din; i += 256) { float v = xr[i]; xs += v*v; }
  for (int i = threadIdx.x; i < dout; i += 256) {
    float v = mr[i], b = bias[i];
    ms += v*v; mb += v*b; bb += b*b;
  }
  block_reduce_sum4(xs, ms, mb, bb, sbuf);
  float xn  = sqrtf(fmaxf(xs, 1e-15f));
  float mxn = sqrtf(fmaxf(ms, 1e-15f));
  float art = atanhf(fminf(xn, 1.f - 1e-5f));
  float scm = tanhf(mxn/xn*art)/mxn;
  float x2 = scm*scm*ms;
  float y2 = bb;
  float xy = scm*mb;
  float den = fmaxf(1.f + 2.f*xy + x2*y2, 1e-15f);
  float ca = (1.f + 2.f*xy + y2) * scm / den;
  float cb = (1.f - x2) / den;
  for (int i = threadIdx.x; i < dout; i += 256)
    orow[i] = ca*mr[i] + cb*bias[i];
}

__global__ __launch_bounds__(256) void hyp_linear_post(const float* __restrict__ X,
                                                       const float* __restrict__ MX,
                                                       const float* __restrict__ bias,
                                                       float* __restrict__ out,
                                                       int din, int dout) {
  __shared__ float sbuf[16];
  int r = blockIdx.x;
  hyp_post_row(X + (size_t)r*din, MX + (size_t)r*dout, bias, out + (size_t)r*dout,
               din, dout, sbuf);
}

// fused QKV post: blockIdx.y = 0/1/2 -> q/k/v
__global__ __launch_bounds__(256) void qkv_post(const float* __restrict__ X,
                                                const float* __restrict__ MQ,
                                                const float* __restrict__ MK,
                                                const float* __restrict__ MV,
                                                const float* __restrict__ bq,
                                                const float* __restrict__ bk,
                                                const float* __restrict__ bv,
                                                float* __restrict__ oq,
                                                float* __restrict__ ok,
                                                float* __restrict__ ov) {
  __shared__ float sbuf[16];
  int r = blockIdx.x;
  const float* MX = MQ; const float* b = bq; float* o = oq;
  if (blockIdx.y == 1) { MX = MK; b = bk; o = ok; }
  else if (blockIdx.y == 2) { MX = MV; b = bv; o = ov; }
  hyp_post_row(X + (size_t)r*DMODEL, MX + (size_t)r*DMODEL, b, o + (size_t)r*DMODEL,
               DMODEL, DMODEL, sbuf);
}

// ---------- logmap0 per 64-elem head-row ----------
__global__ __launch_bounds__(256) void logmap0_rows64(const float* __restrict__ v,
                                                      float* __restrict__ lv, int nrows) {
  int row = blockIdx.x*4 + (threadIdx.x >> 6);
  if (row >= nrows) return;
  int lane = threadIdx.x & 63;
  float vv = v[(size_t)row*64 + lane];
  float s2 = vv*vv;
  #pragma unroll
  for (int off = 32; off; off >>= 1) s2 += __shfl_xor(s2, off);
  float n = sqrtf(fmaxf(s2, 1e-15f));
  float scl = atanhf(fminf(n, 1.f - 1e-5f))/n;
  lv[(size_t)row*64 + lane] = scl*vv;
}

// ---------- fused: scores + softmax + PV + expmap0, one block per (b,h,i) ----------
__global__ __launch_bounds__(256) void attn_fused(const float* __restrict__ q,
                                                  const float* __restrict__ k,
                                                  const float* __restrict__ lv,
                                                  const float* __restrict__ hs,
                                                  float* __restrict__ ao,
                                                  short* __restrict__ aob) {
  __shared__ float qs[DHEAD];
  __shared__ float p[SEQ];
  __shared__ float sbuf[4];
  __shared__ float pv[4][DHEAD];
  int idx = blockIdx.x;            // (b*NHEAD + h)*SEQ + i
  int i  = idx % SEQ;
  int bh = idx / SEQ;
  int h  = bh % NHEAD;
  int b  = bh / NHEAD;
  const float maxn = 1.0f - 1e-5f;
  const float* qr = q + ((size_t)(b*SEQ + i)*DMODEL) + h*DHEAD;
  if (threadIdx.x < DHEAD) qs[threadIdx.x] = fminf(qr[threadIdx.x], maxn);
  __syncthreads();
  float q2 = 0.f;
  #pragma unroll
  for (int d = 0; d < DHEAD; ++d) q2 += qs[d]*qs[d];
  int j = threadIdx.x;
  float sval = -1e30f;
  if (j < SEQ) {
    const float* kr = k + ((size_t)(b*SEQ + j)*DMODEL) + h*DHEAD;
    float kq = 0.f, k2 = 0.f;
    #pragma unroll
    for (int d = 0; d < DHEAD; ++d) {
      float kv = fminf(kr[d], maxn);
      kq += kv*qs[d]; k2 += kv*kv;
    }
    float xy = -kq;
    float al = 1.f + 2.f*xy + q2;
    float be = 1.f - k2;
    float num2 = al*al*k2 + 2.f*al*be*xy + be*be*q2;
    float den  = fmaxf(1.f + 2.f*xy + k2*q2, 1e-15f);
    float dns  = num2/(den*den);
    float denom = (1.f - q2)*(1.f - k2) + 1e-15f;
    float arg = 1.f + 2.f*dns/denom;
    arg = fmaxf(arg, 1.f + 1e-7f);
    float dist = logf(arg + sqrtf(arg*arg - 1.f));
    sval = -dist / (hs[h] * 8.0f);
  }
  // softmax over j
  int wid = threadIdx.x >> 6, lane = threadIdx.x & 63;
  float m = sval;
  #pragma unroll
  for (int off = 32; off; off >>= 1) m = fmaxf(m, __shfl_xor(m, off));
  if (lane == 0) sbuf[wid] = m;
  __syncthreads();
  m = fmaxf(fmaxf(sbuf[0], sbuf[1]), fmaxf(sbuf[2], sbuf[3]));
  __syncthreads();
  float e = (j < SEQ) ? expf(sval - m) : 0.f;
  float ssum = e;
  #pragma unroll
  for (int off = 32; off; off >>= 1) ssum += __shfl_xor(ssum, off);
  if (lane == 0) sbuf[wid] = ssum;
  __syncthreads();
  ssum = sbuf[0] + sbuf[1] + sbuf[2] + sbuf[3];
  if (j < SEQ) p[j] = e / ssum;
  __syncthreads();
  // PV: wave w sums j in [49w, 49w+49), lane = head dim
  float acc = 0.f;
  const float* lvb = lv + (size_t)(b*SEQ)*DMODEL + h*DHEAD + lane;
  #pragma unroll 7
  for (int jj = wid*49; jj < wid*49 + 49; ++jj)
    acc += p[jj] * lvb[(size_t)jj*DMODEL];
  pv[wid][lane] = acc;
  __syncthreads();
  if (wid == 0) {
    float val = pv[0][lane] + pv[1][lane] + pv[2][lane] + pv[3][lane];
    float s2 = val*val;
    #pragma unroll
    for (int off = 32; off; off >>= 1) s2 += __shfl_xor(s2, off);
    float n = sqrtf(fmaxf(s2, 1e-15f));
    float scl = tanhf(n)/n;
    float o = scl*val;
    size_t oidx = (size_t)(b*SEQ + i)*DMODEL + h*DHEAD + lane;
    ao[oidx] = o;
    aob[oidx] = f2bf(o);
  }
}

// ---------- residual + hyp layer norm (optional bf16 copy) ----------
__global__ __launch_bounds__(256) void resid_ln(const float* __restrict__ X,
                                                const float* __restrict__ Y,
                                                const float* __restrict__ betap,
                                                const float* __restrict__ lnw,
                                                const float* __restrict__ lnb,
                                                float* __restrict__ out,
                                                short* __restrict__ outb) {
  __shared__ float sbuf[16];
  int r = blockIdx.x;
  const float* xr = X + (size_t)r*DMODEL;
  const float* yr = Y + (size_t)r*DMODEL;
  float xv[3], yv[3];
  float x2 = 0.f, yy = 0.f, xy = 0.f, dm = 0.f;
  #pragma unroll
  for (int l = 0; l < 3; ++l) {
    int i = threadIdx.x + l*256;
    xv[l] = xr[i]; yv[l] = yr[i];
    x2 += xv[l]*xv[l]; yy += yv[l]*yv[l]; xy += xv[l]*yv[l];
  }
  block_reduce_sum4(x2, yy, xy, dm, sbuf);
  float beta = betap[0];
  float ny = sqrtf(fmaxf(yy, 1e-15f));
  float scs = tanhf(beta * atanhf(fminf(ny, 1.f - 1e-5f))) / ny;
  float y2  = scs*scs*yy;
  float xys = scs*xy;
  float den = fmaxf(1.f + 2.f*xys + x2*y2, 1e-15f);
  float ca = (1.f + 2.f*xys + y2)/den;
  float cb = (1.f - x2)*scs/den;
  float hv[3]; float h2 = 0.f;
  #pragma unroll
  for (int l = 0; l < 3; ++l) { hv[l] = ca*xv[l] + cb*yv[l]; h2 += hv[l]*hv[l]; }
  float z1 = 0.f, z2 = 0.f, z3 = 0.f;
  block_reduce_sum4(h2, z1, z2, z3, sbuf);
  float nh = sqrtf(fmaxf(h2, 1e-15f));
  float scl = atanhf(fminf(nh, 1.f - 1e-5f))/nh;
  float tv[3]; float tsum = 0.f, tsq = 0.f;
  #pragma unroll
  for (int l = 0; l < 3; ++l) { tv[l] = scl*hv[l]; tsum += tv[l]; tsq += tv[l]*tv[l]; }
  float zz = 0.f, zw = 0.f;
  block_reduce_sum4(tsum, tsq, zz, zw, sbuf);
  float mu  = tsum * (1.f/768.f);
  float var = tsq * (1.f/768.f) - mu*mu;
  float rstd = rsqrtf(var + 1e-5f);
  float lnv[3]; float l2 = 0.f;
  #pragma unroll
  for (int l = 0; l < 3; ++l) {
    int i = threadIdx.x + l*256;
    lnv[l] = (tv[l] - mu)*rstd*lnw[i] + lnb[i];
    l2 += lnv[l]*lnv[l];
  }
  float w1 = 0.f, w2 = 0.f, w3 = 0.f;
  block_reduce_sum4(l2, w1, w2, w3, sbuf);
  float nl = sqrtf(fmaxf(l2, 1e-15f));
  float sce = tanhf(nl)/nl;
  #pragma unroll
  for (int l = 0; l < 3; ++l) {
    int i = threadIdx.x + l*256;
    float o = sce*lnv[l];
    out[(size_t)r*DMODEL + i] = o;
    if (outb) outb[(size_t)r*DMODEL + i] = f2bf(o);
  }
}

// ---------- mobius relu on FF rows (in place) + bf16 copy ----------
__global__ __launch_bounds__(256) void mobius_relu(float* __restrict__ f,
                                                   short* __restrict__ fb) {
  __shared__ float sbuf[16];
  int r = blockIdx.x;
  float* fr = f + (size_t)r*DFF;
  short* fbr = fb + (size_t)r*DFF;
  float fv[12];
  float s2 = 0.f, z1 = 0.f, z2 = 0.f, z3 = 0.f;
  #pragma unroll
  for (int l = 0; l < 12; ++l) { fv[l] = fr[threadIdx.x + l*256]; s2 += fv[l]*fv[l]; }
  block_reduce_sum4(s2, z1, z2, z3, sbuf);
  float n = sqrtf(fmaxf(s2, 1e-15f));
  float scl = atanhf(fminf(n, 1.f - 1e-5f))/n;
  float rv[12]; float r2 = 0.f;
  #pragma unroll
  for (int l = 0; l < 12; ++l) { rv[l] = fmaxf(scl*fv[l], 0.f); r2 += rv[l]*rv[l]; }
  float w1 = 0.f, w2 = 0.f, w3 = 0.f;
  block_reduce_sum4(r2, w1, w2, w3, sbuf);
  float nr = sqrtf(fmaxf(r2, 1e-15f));
  float sce = tanhf(nr)/nr;
  #pragma unroll
  for (int l = 0; l < 12; ++l) {
    float o = sce*rv[l];
    fr[threadIdx.x + l*256] = o;
    fbr[threadIdx.x + l*256] = f2bf(o);
  }
}

extern "C" void kernel_launch(void* const* d_in, const int* in_sizes, int n_in,
                              void* d_out, int out_size, void* d_ws, size_t ws_size,
                              hipStream_t stream) {
  const float* x    = (const float*)d_in[0];
  const float* wq   = (const float*)d_in[1];
  const float* bq   = (const float*)d_in[2];
  const float* wk   = (const float*)d_in[3];
  const float* bk   = (const float*)d_in[4];
  const float* wv   = (const float*)d_in[5];
  const float* bv   = (const float*)d_in[6];
  const float* wo   = (const float*)d_in[7];
  const float* bo   = (const float*)d_in[8];
  const float* hs   = (const float*)d_in[9];
  const float* w1   = (const float*)d_in[10];
  const float* b1   = (const float*)d_in[11];
  const float* w2   = (const float*)d_in[12];
  const float* b2   = (const float*)d_in[13];
  const float* beta = (const float*)d_in[14];
  const float* ln1w = (const float*)d_in[15];
  const float* ln1b = (const float*)d_in[16];
  const float* ln2w = (const float*)d_in[17];
  const float* ln2b = (const float*)d_in[18];
  float* out = (float*)d_out;

  char* base = (char*)d_ws;
  size_t off = 0;
  auto allocB = [&](size_t bytes) {
    off = (off + 63) & ~(size_t)63;
    void* p = base + off; off += bytes; return p;
  };
  short* bfp  = (short*)allocB((size_t)BF_TOTAL * 2);          // bf16 pool: xb + weights
  short* aob  = (short*)allocB((size_t)NROWS*DMODEL * 2);
  short* hbb  = (short*)allocB((size_t)NROWS*DMODEL * 2);
  short* fbb  = (short*)allocB((size_t)NROWS*DFF * 2);
  float* tq   = (float*)allocB((size_t)NROWS*DMODEL * 4);
  float* tk   = (float*)allocB((size_t)NROWS*DMODEL * 4);      // later: aop
  float* tv   = (float*)allocB((size_t)NROWS*DMODEL * 4);      // later: f2
  float* qb   = (float*)allocB((size_t)NROWS*DMODEL * 4);
  float* kb   = (float*)allocB((size_t)NROWS*DMODEL * 4);
  float* vb   = (float*)allocB((size_t)NROWS*DMODEL * 4);
  float* lv   = (float*)allocB((size_t)NROWS*DMODEL * 4);
  float* ao   = (float*)allocB((size_t)NROWS*DMODEL * 4);
  float* hb   = (float*)allocB((size_t)NROWS*DMODEL * 4);
  float* tmpF = (float*)allocB((size_t)NROWS*DFF * 4);
  float* fbuf = (float*)allocB((size_t)NROWS*DFF * 4);

  const short* xb  = bfp + XB_OFF;
  const short* wqb = bfp + WQ_OFF;
  const short* wkb = bfp + WK_OFF;
  const short* wvb = bfp + WV_OFF;
  const short* wob = bfp + WO_OFF;
  const short* w1b = bfp + W1_OFF;
  const short* w2b = bfp + W2_OFF;

  dim3 blk(256);
  dim3 gCVT(1152, 7);
  dim3 gQKV(DMODEL/64, (NROWS+63)/64, 3);   // 12 x 7 x 3
  dim3 gD(DMODEL/64,  (NROWS+63)/64, 1);    // 12 x 7
  dim3 gF(DFF/64,     (NROWS+63)/64, 1);    // 48 x 7

  // convert x + all weights to bf16
  cvt_bf16<<<gCVT, blk, 0, stream>>>(x, wq, wk, wv, wo, w1, w2, bfp);

  // QKV projections
  gemm_bf16<<<gQKV, blk, 0, stream>>>(xb, wqb, wkb, wvb, tq, tk, tv, NROWS, DMODEL, DMODEL);
  qkv_post<<<dim3(NROWS,3), blk, 0, stream>>>(x, tq, tk, tv, bq, bk, bv, qb, kb, vb);

  // attention
  logmap0_rows64<<<(NHROWS+3)/4, blk, 0, stream>>>(vb, lv, NHROWS);
  attn_fused<<<BATCH*NHEAD*SEQ, blk, 0, stream>>>(qb, kb, lv, hs, ao, aob);

  // output projection
  gemm_bf16<<<gD, blk, 0, stream>>>(aob, wob, wob, wob, tq, tq, tq, NROWS, DMODEL, DMODEL);
  hyp_linear_post<<<NROWS, blk, 0, stream>>>(ao, tq, bo, tk, DMODEL, DMODEL);

  // residual 1 + hyp layer norm
  resid_ln<<<NROWS, blk, 0, stream>>>(x, tk, beta, ln1w, ln1b, hb, hbb);

  // FFN
  gemm_bf16<<<gF, blk, 0, stream>>>(hbb, w1b, w1b, w1b, tmpF, tmpF, tmpF, NROWS, DMODEL, DFF);
  hyp_linear_post<<<NROWS, blk, 0, stream>>>(hb, tmpF, b1, fbuf, DMODEL, DFF);
  mobius_relu<<<NROWS, blk, 0, stream>>>(fbuf, fbb);
  gemm_bf16<<<gD, blk, 0, stream>>>(fbb, w2b, w2b, w2b, tq, tq, tq, NROWS, DFF, DMODEL);
  hyp_linear_post<<<NROWS, blk, 0, stream>>>(fbuf, tq, b2, tv, DFF, DMODEL);

  // residual 2 + hyp layer norm -> out
  resid_ln<<<NROWS, blk, 0, stream>>>(hb, tv, beta, ln2w, ln2b, out, nullptr);
}